// Round 9
// baseline (436.153 us; speedup 1.0000x reference)
//
#include <hip/hip_runtime.h>
#include <hip/hip_cooperative_groups.h>
#include <math.h>

namespace cg = cooperative_groups;

// Problem constants
#define IMGS 256
#define NANG 50
#define BATCH 4
#define NCNN 32
#define PIX (IMGS*IMGS)              // 65536
#define NPIX (BATCH*PIX)             // 262144

// Padded channel-last h1: [258][258][32] bf16 per batch
#define PROW 258
#define PPIX (PROW*PROW)
#define PB   (PPIX*NCNN)             // 2130048 bf16 per batch

// Workspace layout (float offsets)
#define OFF_FILT  0          // 51200 filtered sinogram (b,a,s)
#define OFF_H1P   51200      // 4*PB bf16 = 4260096 floats

static constexpr double PI_D = 3.14159265358979323846;

typedef unsigned short u16;
typedef unsigned int   u32;
typedef unsigned long long u64;
typedef __bf16 bfrag __attribute__((ext_vector_type(8)));
typedef float  ffrag __attribute__((ext_vector_type(4)));

__device__ __forceinline__ u16 f2bf(float f) {
    u32 u = __float_as_uint(f);
    u += 0x7fffu + ((u >> 16) & 1u);     // RNE
    return (u16)(u >> 16);
}

#define RPITCH_D 131            // dwords per LDS image row (odd => bank-friendly)
#define H2PITCH 34              // u16 per px slot (32 ch + 2 pad) = 17 dwords

// Single cooperative kernel: 256 blocks x 1024 threads, 1 block/CU (142 KB LDS).
// Phase A: radon forward + ramp filter -> ws[FILT]   (blocks 0..199; w2->LDS n/a)
// Phase B: backproj + y_upd out + conv1 -> h1p       (512 virtual 2-row tiles)
// Phase C: conv2 MFMA -> LDS h2 + conv3 -> out       (512 virtual 2-row tiles)
__global__ __launch_bounds__(1024, 4) void k_fused(
    const float* __restrict__ xsino, const float* __restrict__ yprev,
    const float* __restrict__ yconc, const float* __restrict__ angles,
    const float* __restrict__ stepp, const float* __restrict__ w1,
    const float* __restrict__ b1, const float* __restrict__ w2,
    const float* __restrict__ b2, const float* __restrict__ w3,
    const float* __restrict__ b3, float* __restrict__ ws,
    float* __restrict__ dout)
{
    __shared__ __align__(16) char smem[142400];
    cg::grid_group grid = cg::this_grid();
    int tid = threadIdx.x, bid = blockIdx.x;

    // ===================== Phase A: radon + ramp filter =====================
    if (bid < 200) {
        u16* limg   = (u16*)smem;                    // 258*262 u16 = 135192 B
        u32* l32    = (u32*)smem;
        float* spart = (float*)(smem + 135232);      // 1024 floats
        float* staps = (float*)(smem + 139328);      // 512 floats
        float* srow  = (float*)(smem + 141376);      // 256 floats
        int ra = bid;                                // b*50 + a
        int a = ra % NANG, b = ra / NANG;

        // ramp taps, closed form:
        // g[n]*512 = (-1)^n + S(n)/128, S(n)=sum_{k=1}^{255} k cos(k pi n/256)
        //          = (256cos(255t)-255cos(256t)-1)/(2(1-cos t)), t = pi n/256.
        if (tid < 511) {
            int d = tid - 255;
            int n = d < 0 ? -d : d;
            double g;
            if (n == 0) {
                g = 0.5;
            } else {
                double th = PI_D * (double)n / 256.0;
                double S = (256.0 * cos(255.0 * th) - 255.0 * cos(256.0 * th) - 1.0)
                           / (2.0 * (1.0 - cos(th)));
                double sign = (n & 1) ? -1.0 : 1.0;
                g = (sign + S / 128.0) / 512.0;
            }
            staps[tid] = (float)(g * PI_D / 100.0);   // fold pi/(2A), A=50
        }
        // zero image borders
        for (int z = tid; z < 772; z += 1024) {
            int addr;
            if (z < 258)      addr = z * RPITCH_D;
            else if (z < 516) addr = (z - 258) * RPITCH_D + 129;
            else if (z < 644) addr = (z - 516) + 1;
            else              addr = 257 * RPITCH_D + (z - 644) + 1;
            l32[addr] = 0;
        }
        // stage interior: mask inline, fp32 -> bf16
        const float* __restrict__ src = yprev + b * PIX;
        for (int idx = tid; idx < 16384; idx += 1024) {
            int r = idx >> 6, c4 = (idx & 63) << 2;
            float4 v = *(const float4*)(src + r * 256 + c4);
            float di = (float)r - 127.5f;
            float rr = di * di;
            float d0 = (float)c4 - 127.5f;
            v.x = (rr + d0 * d0 <= 16384.0f) ? v.x : 0.0f;
            v.y = (rr + (d0 + 1.0f) * (d0 + 1.0f) <= 16384.0f) ? v.y : 0.0f;
            v.z = (rr + (d0 + 2.0f) * (d0 + 2.0f) <= 16384.0f) ? v.z : 0.0f;
            v.w = (rr + (d0 + 3.0f) * (d0 + 3.0f) <= 16384.0f) ? v.w : 0.0f;
            u32 p0 = (u32)f2bf(v.x) | ((u32)f2bf(v.y) << 16);
            u32 p1 = (u32)f2bf(v.z) | ((u32)f2bf(v.w) << 16);
            int dw = (r + 1) * RPITCH_D + (c4 >> 1) + 1;
            l32[dw] = p0; l32[dw + 1] = p1;
        }
        __syncthreads();

        float a_ = angles[a];
        float cs = cosf(a_), sn = sinf(a_);
        int lane = tid & 63, wv_ = tid >> 6;  // 16 waves
        int s8 = lane & 7, t8 = lane >> 3;    // 8x8 patch coords (2D bank spread)
        int sA = wv_ * 16 + s8;               // this thread's s rows: sA, sA+8
        float scA = (float)sA - 127.5f;
        float tc0 = (float)t8 - 127.5f;
        float rowA = scA * sn + tc0 * cs + 127.5f;
        float colA = scA * cs - tc0 * sn + 127.5f;
        float rowB = rowA + 8.0f * sn;
        float colB = colA + 8.0f * cs;
        float cs8 = 8.0f * cs, sn8 = 8.0f * sn;
        float accA = 0.0f, accB = 0.0f;
        #pragma unroll 4
        for (int j = 0; j < 32; ++j) {        // t = t8 + 8j
            #pragma unroll
            for (int hh = 0; hh < 2; ++hh) {
                float rowv = hh ? rowB : rowA;
                float colv = hh ? colB : colA;
                float fr = floorf(rowv), fc = floorf(colv);
                float wr = rowv - fr, wc = colv - fc;
                int i0 = (int)fr, j0 = (int)fc;
                bool valid = (rowv > -1.0f) & (rowv < 256.0f) & (colv > -1.0f) & (colv < 256.0f);
                int i0c = min(max(i0, -1), 255);
                int j0c = min(max(j0, -1), 255);
                int ca = j0c + 2;
                int ka = ca >> 1;
                int sh = (ca & 1) << 4;
                int dw = (i0c + 1) * RPITCH_D + ka;
                u32 A = l32[dw],            C = l32[dw + 1];
                u32 B = l32[dw + RPITCH_D], D = l32[dw + RPITCH_D + 1];
                u32 top = (u32)((((u64)C << 32) | (u64)A) >> sh);
                u32 bot = (u32)((((u64)D << 32) | (u64)B) >> sh);
                float tl = __uint_as_float(top << 16);
                float tr_ = __uint_as_float(top & 0xffff0000u);
                float bl = __uint_as_float(bot << 16);
                float br = __uint_as_float(bot & 0xffff0000u);
                float tv = tl + (tr_ - tl) * wc;
                float bv = bl + (br - bl) * wc;
                float sv = tv + (bv - tv) * wr;
                sv = valid ? sv : 0.0f;
                if (hh) accB += sv; else accA += sv;
            }
            rowA += cs8; colA -= sn8; rowB += cs8; colB -= sn8;
        }
        accA += __shfl_xor(accA, 8, 64);
        accA += __shfl_xor(accA, 16, 64);
        accA += __shfl_xor(accA, 32, 64);
        accB += __shfl_xor(accB, 8, 64);
        accB += __shfl_xor(accB, 16, 64);
        accB += __shfl_xor(accB, 32, 64);
        if (t8 == 0) { spart[sA] = accA; spart[sA + 8] = accB; }
        __syncthreads();
        if (tid < 256)
            srow[tid] = spart[tid] - xsino[ra * 256 + tid];
        __syncthreads();
        {   // 511-tap filter, split 4 ways over taps
            int s = tid & 255, q = tid >> 8;
            float fa = 0.0f;
            int m0 = q * 64;
            #pragma unroll 8
            for (int m = m0; m < m0 + 64; ++m) fa += srow[m] * staps[s - m + 255];
            spart[tid] = fa;
        }
        __syncthreads();
        if (tid < 256)
            ws[OFF_FILT + ra * 256 + tid] =
                spart[tid] + spart[tid + 256] + spart[tid + 512] + spart[tid + 768];
    }
    __threadfence();
    grid.sync();

    // ===================== Phase B: backproj + conv1 =====================
    {
        float* sf          = (float*)smem;                 // 50*256 floats
        float (*supd)[258] = (float(*)[258])(smem + 51200);
        float (*sy2)[258]  = (float(*)[258])(smem + 55328);
        float* scs         = (float*)(smem + 59456);
        float* ssn         = (float*)(smem + 59656);
        float step = stepp[0];
        for (int vt = bid; vt < 512; vt += 256) {
            int b = vt >> 7, tile = vt & 127, y0 = tile << 1;
            {   // stage sf via float4
                const float4* s4 = (const float4*)(ws + OFF_FILT + b * (NANG * 256));
                float4* d4 = (float4*)sf;
                for (int idx = tid; idx < NANG * 64; idx += 1024) d4[idx] = s4[idx];
            }
            if (tid < NANG) {
                float a_ = angles[tid];
                scs[tid] = cosf(a_); ssn[tid] = sinf(a_);
            }
            if (tid < 8) supd[tid >> 1][(tid & 1) * 257] = 0.0f;
            for (int idx = tid; idx < 4 * 258; idx += 1024) {
                int r = idx / 258, x = idx % 258;
                int iy = y0 - 1 + r, ix = x - 1;
                sy2[r][x] = ((unsigned)iy < 256u && (unsigned)ix < 256u)
                                ? yconc[b * PIX + iy * 256 + ix] : 0.0f;
            }
            // zero h1p borders (this tile's share: 9 border px * 16 dwords)
            if (tid < 144) {
                int px_i = tile * 9 + (tid >> 4), dw = tid & 15;
                if (px_i < 1028) {
                    int y, x;
                    if (px_i < 516) { y = (px_i < 258) ? 0 : 257; x = px_i % 258; }
                    else            { int j = px_i - 516; y = 1 + (j >> 1); x = (j & 1) * 257; }
                    u32* p = (u32*)((u16*)(ws + OFF_H1P) + b * PB + (y * PROW + x) * NCNN);
                    p[dw] = 0;
                }
            }
            __syncthreads();

            // backproject: exactly one sample per thread (4 rows x 256 cols)
            {
                int r = tid >> 8, j = tid & 255;
                int iy = y0 - 1 + r;
                float val = 0.0f;
                if ((unsigned)iy < 256u) {
                    float yy = (float)iy - 127.5f, xx = (float)j - 127.5f;
                    float acc = 0.0f;
                    #pragma unroll 5
                    for (int a = 0; a < NANG; ++a) {
                        float idxf = xx * scs[a] + yy * ssn[a] + 127.5f;
                        float fl = floorf(idxf);
                        int i0 = (int)fl;
                        i0 = min(max(i0, 0), 254);
                        float w = idxf - (float)i0;
                        float v = sf[a * 256 + i0] * (1.0f - w) + sf[a * 256 + i0 + 1] * w;
                        acc += (idxf >= 0.0f && idxf <= 255.0f) ? v : 0.0f;
                    }
                    float m = (xx * xx + yy * yy <= 16384.0f) ? 1.0f : 0.0f;
                    val = yprev[b * PIX + iy * 256 + j] + step * acc * m;
                    if (r == 1 || r == 2)
                        dout[NPIX + b * PIX + iy * 256 + j] = val;   // second output
                }
                supd[r][j + 1] = val;
            }
            __syncthreads();

            // conv1 (2->32) + relu: wave owns (row, 4 oc); weights in regs
            {
                int wave = tid >> 6, lane = tid & 63;
                int row = wave >> 3, oc0 = (wave & 7) * 4;
                int oy = y0 + row;
                float W[72];
                const float4* wsrc = (const float4*)(w1 + oc0 * 18);
                #pragma unroll
                for (int i = 0; i < 18; ++i) ((float4*)W)[i] = wsrc[i];
                float bb0 = b1[oc0], bb1 = b1[oc0 + 1], bb2 = b1[oc0 + 2], bb3 = b1[oc0 + 3];
                u16* h1base = (u16*)(ws + OFF_H1P) + b * PB;
                #pragma unroll
                for (int it = 0; it < 4; ++it) {
                    int x = it * 64 + lane;
                    float v[18];
                    #pragma unroll
                    for (int ky = 0; ky < 3; ++ky)
                        #pragma unroll
                        for (int kx = 0; kx < 3; ++kx) {
                            v[ky * 3 + kx]     = supd[row + ky][x + kx];
                            v[9 + ky * 3 + kx] = sy2[row + ky][x + kx];
                        }
                    float a0 = bb0, a1 = bb1, a2 = bb2, a3 = bb3;
                    #pragma unroll
                    for (int t = 0; t < 18; ++t) {
                        a0 += v[t] * W[t];
                        a1 += v[t] * W[18 + t];
                        a2 += v[t] * W[36 + t];
                        a3 += v[t] * W[54 + t];
                    }
                    u32 p0 = (u32)f2bf(fmaxf(a0, 0.0f)) | ((u32)f2bf(fmaxf(a1, 0.0f)) << 16);
                    u32 p1 = (u32)f2bf(fmaxf(a2, 0.0f)) | ((u32)f2bf(fmaxf(a3, 0.0f)) << 16);
                    u32* op = (u32*)(h1base + ((oy + 1) * PROW + (x + 1)) * NCNN + oc0);
                    op[0] = p0; op[1] = p1;
                }
            }
            __syncthreads();
        }
    }
    __threadfence();
    grid.sync();

    // ===================== Phase C: conv2 MFMA + conv3 =====================
    {
        u16* sh2 = (u16*)smem;                   // 4*258*H2PITCH u16 = 70176 B
        u32* l32 = (u32*)smem;
        u32* swp = (u32*)(smem + 70176);         // 9*16 packed w3 pairs
        const u16* __restrict__ h1p = (const u16*)(ws + OFF_H1P);
        int wave = tid >> 6, lane = tid & 63;
        int m = lane & 15, quad = lane >> 4;
        // w2 B-fragments: convert on the fly (fp32 -> bf16), held in regs
        bfrag Bf[9][2];
        #pragma unroll
        for (int t = 0; t < 9; ++t) {
            #pragma unroll
            for (int h = 0; h < 2; ++h) {
                int oc = m + 16 * h;
                bfrag f;
                #pragma unroll
                for (int jj = 0; jj < 8; ++jj) {
                    int ic = quad * 8 + jj;
                    u16 bv = f2bf(w2[(oc * 32 + ic) * 9 + t]);
                    f[jj] = *(__bf16*)&bv;
                }
                Bf[t][h] = f;
            }
        }
        float bias0 = b2[m], bias1 = b2[m + 16];
        for (int vt = bid; vt < 512; vt += 256) {
            int b = vt >> 7, tile = vt & 127, y0 = tile << 1;
            if (tid < 144) {
                int t = tid >> 4, kd = tid & 15;
                swp[tid] = (u32)f2bf(w3[(2 * kd) * 9 + t]) | ((u32)f2bf(w3[(2 * kd + 1) * 9 + t]) << 16);
            }
            if (tid < 136) {
                int r = tid / 34, rem = tid % 34;
                int col = (rem < 17) ? 0 : 257, dw = rem % 17;
                l32[(r * 258 + col) * 17 + dw] = 0;
            }
            #pragma unroll
            for (int r = 0; r < 4; ++r) {
                int hy = y0 - 1 + r;
                if (hy < 0 || hy > 255)
                    for (int idx = tid; idx < 258 * 17; idx += 1024)
                        l32[r * 258 * 17 + idx] = 0;
            }
            __syncthreads();

            // conv2 MFMA: 64 (row, 16px) tiles over 16 waves
            const u16* __restrict__ h1b = h1p + b * PB;
            #pragma unroll
            for (int k = 0; k < 4; ++k) {
                int tl = wave + (k << 4);        // 0..63
                int ridx = tl >> 4, xt = tl & 15;
                int hy = y0 - 1 + ridx;
                bool valid = (unsigned)hy < 256u;
                int hyc = min(max(hy, 0), 255);
                int xs = xt << 4;
                bfrag A0[3], A1[3];
                #pragma unroll
                for (int tx = 0; tx < 3; ++tx)
                    A0[tx] = *(const bfrag*)(h1b + ((hyc + 0) * PROW + xs + m + tx) * NCNN + quad * 8);
                #pragma unroll
                for (int tx = 0; tx < 3; ++tx)
                    A1[tx] = *(const bfrag*)(h1b + ((hyc + 1) * PROW + xs + m + tx) * NCNN + quad * 8);
                ffrag c0 = {0.f, 0.f, 0.f, 0.f}, c1 = {0.f, 0.f, 0.f, 0.f};
                #pragma unroll
                for (int tx = 0; tx < 3; ++tx) {
                    c0 = __builtin_amdgcn_mfma_f32_16x16x32_bf16(A0[tx], Bf[tx][0], c0, 0, 0, 0);
                    c1 = __builtin_amdgcn_mfma_f32_16x16x32_bf16(A0[tx], Bf[tx][1], c1, 0, 0, 0);
                }
                #pragma unroll
                for (int tx = 0; tx < 3; ++tx)
                    A0[tx] = *(const bfrag*)(h1b + ((hyc + 2) * PROW + xs + m + tx) * NCNN + quad * 8);
                #pragma unroll
                for (int tx = 0; tx < 3; ++tx) {
                    c0 = __builtin_amdgcn_mfma_f32_16x16x32_bf16(A1[tx], Bf[3 + tx][0], c0, 0, 0, 0);
                    c1 = __builtin_amdgcn_mfma_f32_16x16x32_bf16(A1[tx], Bf[3 + tx][1], c1, 0, 0, 0);
                }
                #pragma unroll
                for (int tx = 0; tx < 3; ++tx) {
                    c0 = __builtin_amdgcn_mfma_f32_16x16x32_bf16(A0[tx], Bf[6 + tx][0], c0, 0, 0, 0);
                    c1 = __builtin_amdgcn_mfma_f32_16x16x32_bf16(A0[tx], Bf[6 + tx][1], c1, 0, 0, 0);
                }
                if (valid) {
                    #pragma unroll
                    for (int r = 0; r < 4; ++r) {
                        int px = xs + quad * 4 + r;
                        u16* op = sh2 + (ridx * 258 + px + 1) * H2PITCH;
                        op[m]      = f2bf(fmaxf(c0[r] + bias0, 0.0f));
                        op[m + 16] = f2bf(fmaxf(c1[r] + bias1, 0.0f));
                    }
                }
            }
            __syncthreads();

            // conv3 (32->1): 2 lanes per px (kd halves), shfl reduce
            {
                int px = tid >> 1, half = tid & 1;
                int rr = px >> 8, x = px & 255;
                int oy = y0 + rr;
                float acc = 0.0f;
                #pragma unroll
                for (int ky = 0; ky < 3; ++ky) {
                    #pragma unroll
                    for (int cx = 0; cx < 3; ++cx) {
                        int t = ky * 3 + cx;
                        const u32* q = l32 + ((rr + ky) * 258 + x + cx) * 17 + half * 8;
                        const u32* wq = swp + t * 16 + half * 8;
                        #pragma unroll
                        for (int kd = 0; kd < 8; ++kd) {
                            u32 hv = q[kd];
                            u32 wvv = wq[kd];
                            float h0 = __uint_as_float(hv << 16);
                            float h1 = __uint_as_float(hv & 0xffff0000u);
                            float w0 = __uint_as_float(wvv << 16);
                            float w1_ = __uint_as_float(wvv & 0xffff0000u);
                            acc += h0 * w0 + h1 * w1_;
                        }
                    }
                }
                acc += __shfl_xor(acc, 1, 64);
                if (half == 0)
                    dout[b * PIX + oy * 256 + x] = acc + b3[0];   // first output
            }
            __syncthreads();
        }
    }
}

extern "C" void kernel_launch(void* const* d_in, const int* in_sizes, int n_in,
                              void* d_out, int out_size, void* d_ws, size_t ws_size,
                              hipStream_t stream) {
    const float* xsino  = (const float*)d_in[0];
    const float* yprev  = (const float*)d_in[1];
    const float* yconc  = (const float*)d_in[2];
    const float* angles = (const float*)d_in[3];
    const float* stepp  = (const float*)d_in[4];
    const float* w1 = (const float*)d_in[5];
    const float* b1 = (const float*)d_in[6];
    const float* w2 = (const float*)d_in[7];
    const float* b2 = (const float*)d_in[8];
    const float* w3 = (const float*)d_in[9];
    const float* b3 = (const float*)d_in[10];
    float* out = (float*)d_out;
    float* ws  = (float*)d_ws;

    void* args[] = {(void*)&xsino, (void*)&yprev, (void*)&yconc, (void*)&angles,
                    (void*)&stepp, (void*)&w1, (void*)&b1, (void*)&w2, (void*)&b2,
                    (void*)&w3, (void*)&b3, (void*)&ws, (void*)&out};
    hipLaunchCooperativeKernel((const void*)k_fused, dim3(256), dim3(1024),
                               args, 0, stream);
}

// Round 11
// 155.651 us; speedup vs baseline: 2.8021x; 2.8021x over previous
//
#include <hip/hip_runtime.h>
#include <math.h>

// Problem constants
#define IMGS 256
#define NANG 50
#define BATCH 4
#define NCNN 32
#define PIX (IMGS*IMGS)              // 65536
#define NPIX (BATCH*PIX)             // 262144

// Padded channel-last h1: [258][258][32] bf16 per batch
#define PROW 258
#define PPIX (PROW*PROW)
#define PB   (PPIX*NCNN)             // 2130048 bf16 per batch

// Workspace layout (float offsets)
#define OFF_FILT  0          // 51200 filtered sinogram (b,a,s)
#define OFF_W2BF  51200      // 9216 bf16 = 4608 floats ([tap][oc][ic])
#define OFF_H1P   55808      // 4*PB bf16 = 4260096 floats

static constexpr double PI_D = 3.14159265358979323846;

typedef unsigned short u16;
typedef unsigned int   u32;
typedef unsigned long long u64;
typedef __bf16 bfrag __attribute__((ext_vector_type(8)));
typedef float  ffrag __attribute__((ext_vector_type(4)));

__device__ __forceinline__ u16 f2bf(float f) {
    u32 u = __float_as_uint(f);
    u += 0x7fffu + ((u >> 16) & 1u);     // RNE
    return (u16)(u >> 16);
}

// =========== K_A: radon forward + ramp filter (fused), + w2->bf16 ===========
// blocks [0,200): one per (b,a), 1024 threads. 8x8 (s x t) lane patches for 2D
// bank spread. Per-wave t-window from the circle bound: a sample at (s,t) is
// nonzero only if s_c^2+t_c^2 <= (128+sqrt2)^2 (rotation preserves radius; all
// 4 bilinear neighbors masked-zero/OOB beyond). Window sized from the wave's
// MINIMUM |s_c| (widest lane) — R10 wrongly used the max (narrowest) and
// dropped valid samples.
// blocks [200,209): w2 -> bf16 [tap][oc][ic]
#define RPITCH_D 131            // dwords per LDS image row (odd => bank-friendly)
__global__ __launch_bounds__(1024, 4) void k_A(const float* __restrict__ angles,
                                               const float* __restrict__ yprev,
                                               const float* __restrict__ xsino,
                                               const float* __restrict__ w2,
                                               float* __restrict__ ws) {
    __shared__ u16 limg[258 * 262];      // 135,192 B
    __shared__ float spart[1024];
    __shared__ float staps[512];
    __shared__ float srow[256];
    int tid = threadIdx.x;
    int gid = blockIdx.x;
    if (gid >= 200) {                    // w2 conversion blocks
        int i = (gid - 200) * 1024 + tid;
        if (i < 9216) {
            int t = i >> 10, oc = (i >> 5) & 31, ic = i & 31;
            ((u16*)(ws + OFF_W2BF))[i] = f2bf(w2[(oc * 32 + ic) * 9 + t]);
        }
        return;
    }
    u32* l32 = (u32*)limg;
    int ra = gid;                        // b*50 + a
    int a = ra % NANG, b = ra / NANG;

    // ramp taps, closed form:
    // g[n]*512 = (-1)^n + S(n)/128, S(n)=sum_{k=1}^{255} k cos(k pi n/256)
    //          = (256cos(255t)-255cos(256t)-1)/(2(1-cos t)), t = pi n/256.
    if (tid < 511) {
        int d = tid - 255;
        int n = d < 0 ? -d : d;
        double g;
        if (n == 0) {
            g = 0.5;
        } else {
            double th = PI_D * (double)n / 256.0;
            double S = (256.0 * cos(255.0 * th) - 255.0 * cos(256.0 * th) - 1.0)
                       / (2.0 * (1.0 - cos(th)));
            double sign = (n & 1) ? -1.0 : 1.0;
            g = (sign + S / 128.0) / 512.0;
        }
        staps[tid] = (float)(g * PI_D / 100.0);   // fold pi/(2A), A=50
    }

    // zero image borders
    for (int z = tid; z < 772; z += 1024) {
        int addr;
        if (z < 258)      addr = z * RPITCH_D;
        else if (z < 516) addr = (z - 258) * RPITCH_D + 129;
        else if (z < 644) addr = (z - 516) + 1;
        else              addr = 257 * RPITCH_D + (z - 644) + 1;
        l32[addr] = 0;
    }
    // stage interior: mask inline, fp32 -> bf16
    const float* __restrict__ src = yprev + b * PIX;
    for (int idx = tid; idx < 16384; idx += 1024) {
        int r = idx >> 6, c4 = (idx & 63) << 2;
        float4 v = *(const float4*)(src + r * 256 + c4);
        float di = (float)r - 127.5f;
        float rr = di * di;
        float d0 = (float)c4 - 127.5f;
        v.x = (rr + d0 * d0 <= 16384.0f) ? v.x : 0.0f;
        v.y = (rr + (d0 + 1.0f) * (d0 + 1.0f) <= 16384.0f) ? v.y : 0.0f;
        v.z = (rr + (d0 + 2.0f) * (d0 + 2.0f) <= 16384.0f) ? v.z : 0.0f;
        v.w = (rr + (d0 + 3.0f) * (d0 + 3.0f) <= 16384.0f) ? v.w : 0.0f;
        u32 p0 = (u32)f2bf(v.x) | ((u32)f2bf(v.y) << 16);
        u32 p1 = (u32)f2bf(v.z) | ((u32)f2bf(v.w) << 16);
        int dw = (r + 1) * RPITCH_D + (c4 >> 1) + 1;
        l32[dw] = p0; l32[dw + 1] = p1;
    }
    __syncthreads();

    float a_ = angles[a];
    float cs = cosf(a_), sn = sinf(a_);
    int lane = tid & 63, wv_ = tid >> 6;  // 16 waves
    int s8 = lane & 7, t8 = lane >> 3;    // 8x8 patch coords
    int sA = wv_ * 16 + s8;               // this thread's two s rows: sA, sA+8
    // circle-bounded t-window for this wave: use MIN |s_c| over s in
    // [wv*16, wv*16+16) (widest lane). Endpoints share sign (127.5 non-integer).
    float e0 = fabsf((float)(wv_ * 16) - 127.5f);
    float e1 = fabsf((float)(wv_ * 16 + 15) - 127.5f);
    float smin = fminf(e0, e1);
    float t_lim = sqrtf(16758.0f - smin * smin);  // (128+sqrt2)^2 = 16748.04 < 16758
    int jmin = max(0, (int)ceilf((120.5f - t_lim) * 0.125f));
    int jmax = min(31, (int)floorf((127.5f + t_lim) * 0.125f));

    float scA = (float)sA - 127.5f;
    float tc0 = (float)(t8 + 8 * jmin) - 127.5f;
    float rowA = scA * sn + tc0 * cs + 127.5f;
    float colA = scA * cs - tc0 * sn + 127.5f;
    float rowB = rowA + 8.0f * sn;
    float colB = colA + 8.0f * cs;
    float cs8 = 8.0f * cs, sn8 = 8.0f * sn;
    float accA = 0.0f, accB = 0.0f;
    for (int j = jmin; j <= jmax; ++j) {  // t = t8 + 8j
        #pragma unroll
        for (int hh = 0; hh < 2; ++hh) {
            float rowv = hh ? rowB : rowA;
            float colv = hh ? colB : colA;
            float fr = floorf(rowv), fc = floorf(colv);
            float wr = rowv - fr, wc = colv - fc;
            int i0 = (int)fr, j0 = (int)fc;
            bool valid = (rowv > -1.0f) & (rowv < 256.0f) & (colv > -1.0f) & (colv < 256.0f);
            int i0c = min(max(i0, -1), 255);
            int j0c = min(max(j0, -1), 255);
            int ca = j0c + 2;
            int ka = ca >> 1;
            int sh = (ca & 1) << 4;
            int dw = (i0c + 1) * RPITCH_D + ka;
            u32 A = l32[dw],            C = l32[dw + 1];
            u32 B = l32[dw + RPITCH_D], D = l32[dw + RPITCH_D + 1];
            u32 top = (u32)((((u64)C << 32) | (u64)A) >> sh);
            u32 bot = (u32)((((u64)D << 32) | (u64)B) >> sh);
            float tl = __uint_as_float(top << 16);
            float tr_ = __uint_as_float(top & 0xffff0000u);
            float bl = __uint_as_float(bot << 16);
            float br = __uint_as_float(bot & 0xffff0000u);
            float tv = tl + (tr_ - tl) * wc;
            float bv = bl + (br - bl) * wc;
            float sv = tv + (bv - tv) * wr;
            sv = valid ? sv : 0.0f;
            if (hh) accB += sv; else accA += sv;
        }
        rowA += cs8; colA -= sn8; rowB += cs8; colB -= sn8;
    }
    // reduce over the 8 t8 lanes (stride-8 butterfly)
    accA += __shfl_xor(accA, 8, 64);
    accA += __shfl_xor(accA, 16, 64);
    accA += __shfl_xor(accA, 32, 64);
    accB += __shfl_xor(accB, 8, 64);
    accB += __shfl_xor(accB, 16, 64);
    accB += __shfl_xor(accB, 32, 64);
    if (t8 == 0) { spart[sA] = accA; spart[sA + 8] = accB; }
    __syncthreads();
    if (tid < 256)
        srow[tid] = spart[tid] - xsino[ra * 256 + tid];
    __syncthreads();
    {   // 511-tap filter, split 4 ways over taps
        int s = tid & 255, q = tid >> 8;
        float fa = 0.0f;
        int m0 = q * 64;
        #pragma unroll 8
        for (int m = m0; m < m0 + 64; ++m) fa += srow[m] * staps[s - m + 255];
        spart[tid] = fa;
    }
    __syncthreads();
    if (tid < 256)
        ws[OFF_FILT + ra * 256 + tid] =
            spart[tid] + spart[tid + 256] + spart[tid + 512] + spart[tid + 768];
}

// =========== K_B: backprojection + y_upd out + conv1 -> h1p ===========
// One block per (b, 2-row tile): 512 blocks x 512 thr, LDS ~60KB -> 2 blocks/CU
// (16 waves). Backproj: 2 interleaved row-chains/thread. Conv1: wave-stationary
// oc (4 oc/wave, 72 weights in VGPRs); y_concat tile staged in LDS.
__global__ __launch_bounds__(512, 4) void k_B(const float* __restrict__ angles,
                                              const float* __restrict__ yprev,
                                              const float* __restrict__ yconc,
                                              const float* __restrict__ stepp,
                                              const float* __restrict__ w1,
                                              const float* __restrict__ b1,
                                              float* __restrict__ ws,
                                              float* __restrict__ dout) {
    __shared__ float sf[NANG * 256];     // 51.2 KB filtered sinogram (batch b)
    __shared__ float supd[4][258];       // y_upd rows y0-1..y0+2 (+col halo)
    __shared__ float sy2[4][258];        // y_concat rows y0-1..y0+2 (+col halo)
    __shared__ float scs[NANG], ssn[NANG];
    int tid = threadIdx.x;
    int b = blockIdx.x >> 7, tile = blockIdx.x & 127;
    int y0 = tile << 1;

    {   // stage sf via float4
        const float4* s4 = (const float4*)(ws + OFF_FILT + b * (NANG * 256));
        float4* d4 = (float4*)sf;
        for (int idx = tid; idx < NANG * 64; idx += 512) d4[idx] = s4[idx];
    }
    if (tid < NANG) {
        float a_ = angles[tid];
        scs[tid] = cosf(a_); ssn[tid] = sinf(a_);
    }
    if (tid < 8) supd[tid >> 1][(tid & 1) * 257] = 0.0f;
    // stage y_concat halo tile
    for (int idx = tid; idx < 4 * 258; idx += 512) {
        int r = idx / 258, x = idx % 258;
        int iy = y0 - 1 + r, ix = x - 1;
        sy2[r][x] = ((unsigned)iy < 256u && (unsigned)ix < 256u)
                        ? yconc[b * PIX + iy * 256 + ix] : 0.0f;
    }
    // zero h1p borders (this block's share: 9 border px * 16 dwords)
    if (tid < 144) {
        int px_i = tile * 9 + (tid >> 4), dw = tid & 15;
        if (px_i < 1028) {
            int y, x;
            if (px_i < 516) { y = (px_i < 258) ? 0 : 257; x = px_i % 258; }
            else            { int j = px_i - 516; y = 1 + (j >> 1); x = (j & 1) * 257; }
            u32* p = (u32*)((u16*)(ws + OFF_H1P) + b * PB + (y * PROW + x) * NCNN);
            p[dw] = 0;
        }
    }
    __syncthreads();

    float step = stepp[0];
    // backproject 4 rows x 256 cols: thread owns col j, rows r0, r0+2
    {
        int j = tid & 255, r0 = tid >> 8;         // r0 in {0,1}
        float xx = (float)j - 127.5f;
        float yy0 = (float)(y0 - 1 + r0) - 127.5f;
        float acc[2] = {0.0f, 0.0f};
        #pragma unroll 5
        for (int a = 0; a < NANG; ++a) {
            float cs = scs[a], sn = ssn[a];
            float f0 = xx * cs + yy0 * sn + 127.5f;
            float idxf[2] = {f0, f0 + sn + sn};
            #pragma unroll
            for (int k = 0; k < 2; ++k) {
                float fl = floorf(idxf[k]);
                int i0 = (int)fl;
                i0 = min(max(i0, 0), 254);
                float w = idxf[k] - (float)i0;
                float v = sf[a * 256 + i0] * (1.0f - w) + sf[a * 256 + i0 + 1] * w;
                acc[k] += (idxf[k] >= 0.0f && idxf[k] <= 255.0f) ? v : 0.0f;
            }
        }
        #pragma unroll
        for (int k = 0; k < 2; ++k) {
            int r = r0 + 2 * k;
            int iy = y0 - 1 + r;
            float val = 0.0f;
            if ((unsigned)iy < 256u) {
                float yy = (float)iy - 127.5f;
                float m = (xx * xx + yy * yy <= 16384.0f) ? 1.0f : 0.0f;
                val = yprev[b * PIX + iy * 256 + j] + step * acc[k] * m;
                if (r >= 1 && r <= 2)
                    dout[NPIX + b * PIX + iy * 256 + j] = val;   // second output
            }
            supd[r][j + 1] = val;
        }
    }
    __syncthreads();

    // conv1 (2->32) + relu: wave w owns oc [4w, 4w+4); weights in VGPRs
    {
        int wave = tid >> 6, lane = tid & 63;
        int oc0 = wave * 4;
        float W[72];
        const float4* wsrc = (const float4*)(w1 + oc0 * 18);
        #pragma unroll
        for (int i = 0; i < 18; ++i) ((float4*)W)[i] = wsrc[i];
        float bb0 = b1[oc0], bb1 = b1[oc0 + 1], bb2 = b1[oc0 + 2], bb3 = b1[oc0 + 3];
        u16* h1base = (u16*)(ws + OFF_H1P) + b * PB;
        #pragma unroll
        for (int it = 0; it < 8; ++it) {
            int px = it * 64 + lane;
            int rr = px >> 8, x = px & 255;
            int oy = y0 + rr;
            float v[18];
            #pragma unroll
            for (int ky = 0; ky < 3; ++ky)
                #pragma unroll
                for (int kx = 0; kx < 3; ++kx) {
                    v[ky * 3 + kx]     = supd[rr + ky][x + kx];
                    v[9 + ky * 3 + kx] = sy2[rr + ky][x + kx];
                }
            float a0 = bb0, a1 = bb1, a2 = bb2, a3 = bb3;
            #pragma unroll
            for (int t = 0; t < 18; ++t) {
                a0 += v[t] * W[t];
                a1 += v[t] * W[18 + t];
                a2 += v[t] * W[36 + t];
                a3 += v[t] * W[54 + t];
            }
            u32 p0 = (u32)f2bf(fmaxf(a0, 0.0f)) | ((u32)f2bf(fmaxf(a1, 0.0f)) << 16);
            u32 p1 = (u32)f2bf(fmaxf(a2, 0.0f)) | ((u32)f2bf(fmaxf(a3, 0.0f)) << 16);
            u32* op = (u32*)(h1base + ((oy + 1) * PROW + (x + 1)) * NCNN + oc0);
            op[0] = p0; op[1] = p1;
        }
    }
}

// =========== K_C: conv2 (MFMA) -> LDS h2 tile + conv3 -> out ===========
// One block per (b, 2-row tile): 512 blocks x 512 thr, LDS ~71KB -> 2 blocks/CU.
#define H2PITCH 34               // u16 per px slot (32 ch + 2 pad) = 17 dwords
__global__ __launch_bounds__(512, 4) void k_C(const float* __restrict__ b2,
                                              const float* __restrict__ w3,
                                              const float* __restrict__ b3,
                                              float* __restrict__ ws,
                                              float* __restrict__ dout) {
    __shared__ u16 sh2[4 * 258 * H2PITCH];   // 70,176 B
    __shared__ u32 swp[9 * 16];              // w3 packed bf16 ch-pairs [t][kd]
    u32* l32 = (u32*)sh2;
    int tid = threadIdx.x;
    int b = blockIdx.x >> 7, tile = blockIdx.x & 127;
    int y0 = tile << 1;

    if (tid < 144) {
        int t = tid >> 4, kd = tid & 15;
        swp[tid] = (u32)f2bf(w3[(2 * kd) * 9 + t]) | ((u32)f2bf(w3[(2 * kd + 1) * 9 + t]) << 16);
    }
    // zero border px columns (stored px 0 and 257) of all 4 rows
    if (tid < 136) {
        int r = tid / 34, rem = tid % 34;
        int col = (rem < 17) ? 0 : 257, dw = rem % 17;
        l32[(r * 258 + col) * 17 + dw] = 0;
    }
    // zero out-of-image rows (edge tiles only)
    #pragma unroll
    for (int r = 0; r < 4; ++r) {
        int hy = y0 - 1 + r;
        if (hy < 0 || hy > 255)
            for (int idx = tid; idx < 258 * 17; idx += 512)
                l32[r * 258 * 17 + idx] = 0;
    }
    __syncthreads();

    // ---- conv2 MFMA: 64 (row, 16px) tiles over 8 waves, pipelined A loads ----
    const u16* __restrict__ w2bf = (const u16*)(ws + OFF_W2BF);
    const u16* __restrict__ h1b  = (const u16*)(ws + OFF_H1P) + b * PB;
    int wave = tid >> 6, lane = tid & 63;
    int m = lane & 15, quad = lane >> 4;
    bfrag Bf[9][2];
    #pragma unroll
    for (int t = 0; t < 9; ++t) {
        const u16* wp = w2bf + t * 1024 + m * 32 + quad * 8;
        Bf[t][0] = *(const bfrag*)(wp);
        Bf[t][1] = *(const bfrag*)(wp + 16 * 32);
    }
    float bias0 = b2[m], bias1 = b2[m + 16];
    #pragma unroll
    for (int k = 0; k < 8; ++k) {
        int tl = wave + (k << 3);        // 0..63
        int ridx = tl >> 4, xt = tl & 15;
        int hy = y0 - 1 + ridx;
        bool valid = (unsigned)hy < 256u;
        int hyc = min(max(hy, 0), 255);
        int xs = xt << 4;
        bfrag A0[3], A1[3];
        #pragma unroll
        for (int tx = 0; tx < 3; ++tx)
            A0[tx] = *(const bfrag*)(h1b + ((hyc + 0) * PROW + xs + m + tx) * NCNN + quad * 8);
        #pragma unroll
        for (int tx = 0; tx < 3; ++tx)
            A1[tx] = *(const bfrag*)(h1b + ((hyc + 1) * PROW + xs + m + tx) * NCNN + quad * 8);
        ffrag c0 = {0.f, 0.f, 0.f, 0.f}, c1 = {0.f, 0.f, 0.f, 0.f};
        #pragma unroll
        for (int tx = 0; tx < 3; ++tx) {
            c0 = __builtin_amdgcn_mfma_f32_16x16x32_bf16(A0[tx], Bf[tx][0], c0, 0, 0, 0);
            c1 = __builtin_amdgcn_mfma_f32_16x16x32_bf16(A0[tx], Bf[tx][1], c1, 0, 0, 0);
        }
        #pragma unroll
        for (int tx = 0; tx < 3; ++tx)
            A0[tx] = *(const bfrag*)(h1b + ((hyc + 2) * PROW + xs + m + tx) * NCNN + quad * 8);
        #pragma unroll
        for (int tx = 0; tx < 3; ++tx) {
            c0 = __builtin_amdgcn_mfma_f32_16x16x32_bf16(A1[tx], Bf[3 + tx][0], c0, 0, 0, 0);
            c1 = __builtin_amdgcn_mfma_f32_16x16x32_bf16(A1[tx], Bf[3 + tx][1], c1, 0, 0, 0);
        }
        #pragma unroll
        for (int tx = 0; tx < 3; ++tx) {
            c0 = __builtin_amdgcn_mfma_f32_16x16x32_bf16(A0[tx], Bf[6 + tx][0], c0, 0, 0, 0);
            c1 = __builtin_amdgcn_mfma_f32_16x16x32_bf16(A0[tx], Bf[6 + tx][1], c1, 0, 0, 0);
        }
        if (valid) {
            #pragma unroll
            for (int r = 0; r < 4; ++r) {
                int px = xs + quad * 4 + r;
                u16* op = sh2 + (ridx * 258 + px + 1) * H2PITCH;
                op[m]      = f2bf(fmaxf(c0[r] + bias0, 0.0f));
                op[m + 16] = f2bf(fmaxf(c1[r] + bias1, 0.0f));
            }
        }
    }
    __syncthreads();

    // ---- conv3 (32->1): 2 adjacent px per thread (shared columns, -33% LDS) ----
    if (tid < 256) {
        int pid = tid * 2;               // 0..510
        int rr = pid >> 8, x = pid & 255;
        int oy = y0 + rr;
        float bias = b3[0];
        float a0 = bias, a1 = bias;
        #pragma unroll
        for (int ky = 0; ky < 3; ++ky) {
            #pragma unroll
            for (int cx = 0; cx < 4; ++cx) {
                const u32* q = l32 + ((rr + ky) * 258 + x + cx) * 17;
                #pragma unroll
                for (int kd = 0; kd < 16; ++kd) {
                    u32 hv = q[kd];
                    float h0 = __uint_as_float(hv << 16);
                    float h1 = __uint_as_float(hv & 0xffff0000u);
                    if (cx < 3) {
                        u32 wv = swp[(ky * 3 + cx) * 16 + kd];
                        a0 += h0 * __uint_as_float(wv << 16)
                            + h1 * __uint_as_float(wv & 0xffff0000u);
                    }
                    if (cx > 0) {
                        u32 wv = swp[(ky * 3 + cx - 1) * 16 + kd];
                        a1 += h0 * __uint_as_float(wv << 16)
                            + h1 * __uint_as_float(wv & 0xffff0000u);
                    }
                }
            }
        }
        float* op = dout + b * PIX + oy * 256 + x;
        op[0] = a0; op[1] = a1;
    }
}

extern "C" void kernel_launch(void* const* d_in, const int* in_sizes, int n_in,
                              void* d_out, int out_size, void* d_ws, size_t ws_size,
                              hipStream_t stream) {
    const float* xsino  = (const float*)d_in[0];
    const float* yprev  = (const float*)d_in[1];
    const float* yconc  = (const float*)d_in[2];
    const float* angles = (const float*)d_in[3];
    const float* stepp  = (const float*)d_in[4];
    const float* w1 = (const float*)d_in[5];
    const float* b1 = (const float*)d_in[6];
    const float* w2 = (const float*)d_in[7];
    const float* b2 = (const float*)d_in[8];
    const float* w3 = (const float*)d_in[9];
    const float* b3 = (const float*)d_in[10];
    float* out = (float*)d_out;
    float* ws  = (float*)d_ws;

    k_A<<<209, 1024, 0, stream>>>(angles, yprev, xsino, w2, ws);
    k_B<<<BATCH * 128, 512, 0, stream>>>(angles, yprev, yconc, stepp, w1, b1, ws, out);
    k_C<<<BATCH * 128, 512, 0, stream>>>(b2, w3, b3, ws, out);
}